// Round 7
// baseline (999.913 us; speedup 1.0000x reference)
//
#include <hip/hip_runtime.h>

#define BB 32
#define TT 128
#define II 256
#define HH 256
#define OO 128
#define FWID 512  // H + I

// d_ws layout:
//   float    hvals[2][BB][HH]   (64 KB)  packed h values, parity double-buffered
//   unsigned sent[BB][16]       (2 KB)   per-(batch, producer-slice) sentinel = latest step published
//
// Protocol (R7, sentinel-based): step s consumes h(s) from hvals[s&1], publishes
// h(s+1) into hvals[(s+1)&1]. A block's sentinel sent[b][sl] = s+1 is written by
// the LAST of its 8 compute waves (LDS release counter, after vmcnt(0) drain of
// that wave's hval stores), so sentinel(s+1) => all 16 rows of (b, slice sl) are
// at the device coherence point. Gatherer for step s polls 16 sentinels >= s
// (64 B, lanes 0-15), acquire-fences, bulk-reads 256 floats, ds_writes, flags.
// Overwrite safety: hvals[q] holding h(s) is overwritten (with h(s+2)) only at
// step s+1 publish, which requires gather(s+1) => sentinel(s+1) from EVERY
// block => each block consumed h(s) => its gatherer's h(s) reads completed.
// Forward progress: sentinel values monotone; induction grounded by memset 0
// (sent=0 >= 0, hvals=0 == h(0)). No XCD/placement assumptions anywhere.

typedef unsigned long long u64;

__device__ __forceinline__ void gather_sent(const unsigned* __restrict__ sent_b,
                                            const float* __restrict__ hv_b,
                                            int lane, unsigned us,
                                            float* dst, int* flag, int fval) {
    // poll 16 sentinels (one cache line), s_sleep backoff to limit fabric traffic
    for (;;) {
        unsigned sv = 0xFFFFFFFFu;
        if (lane < 16)
            sv = __hip_atomic_load(sent_b + lane, __ATOMIC_RELAXED, __HIP_MEMORY_SCOPE_AGENT);
        if (__all(sv >= us)) break;
        __builtin_amdgcn_s_sleep(1);
    }
    __builtin_amdgcn_fence(__ATOMIC_ACQUIRE, "agent");   // order hval reads after poll
    float4 hv;
    hv.x = __hip_atomic_load(hv_b + 4 * lane + 0, __ATOMIC_RELAXED, __HIP_MEMORY_SCOPE_AGENT);
    hv.y = __hip_atomic_load(hv_b + 4 * lane + 1, __ATOMIC_RELAXED, __HIP_MEMORY_SCOPE_AGENT);
    hv.z = __hip_atomic_load(hv_b + 4 * lane + 2, __ATOMIC_RELAXED, __HIP_MEMORY_SCOPE_AGENT);
    hv.w = __hip_atomic_load(hv_b + 4 * lane + 3, __ATOMIC_RELAXED, __HIP_MEMORY_SCOPE_AGENT);
    *reinterpret_cast<float4*>(dst + 4 * lane) = hv;
    if (lane == 0)  // workgroup release drains the wave's ds_write before the flag
        __hip_atomic_store(flag, fval, __ATOMIC_RELEASE, __HIP_MEMORY_SCOPE_WORKGROUP);
}

__global__ __launch_bounds__(640, 1)
void stpn_kernel(const float* __restrict__ x,      // (B,T,I)
                 const float* __restrict__ wlam,   // (H,FWID)
                 const float* __restrict__ wgam,   // (H,FWID)
                 const float* __restrict__ w,      // (H,FWID)
                 const float* __restrict__ bias,   // (H)
                 const float* __restrict__ wout,   // (O,H)
                 const float* __restrict__ bout,   // (O)
                 float* __restrict__ out,          // tag(4096) | h_T(8192) | F_T
                 float* __restrict__ hvals,
                 unsigned* __restrict__ sent)
{
    __shared__ __align__(16) float lh[2][2][HH];   // [A/B][parity][row]
    __shared__ int lflag[2][2];                    // [A/B][parity], monotone s+1
    __shared__ int dctr[2][2];                     // [A/B][parity] publish counters

    const int tid  = threadIdx.x;
    const int bk   = blockIdx.x;
    const int pr   = bk & 15;        // batch pair: batches pr, pr+16
    const int sl   = bk >> 4;        // row slice 0..15
    const int bA   = pr, bB = pr + 16;

    if (tid < 4) ((int*)lflag)[tid] = 0;
    if (tid >= 4 && tid < 8) ((int*)dctr)[tid - 4] = 0;
    __syncthreads();                  // init visible to all 10 waves

    // ================= gatherer waves (tid 512..639) =================
    if (tid >= 512) {
        const int gi   = (tid >> 6) - 8;   // 0 -> batch A, 1 -> batch B
        const int lane = tid & 63;
        const int gb   = gi ? bB : bA;
        const unsigned* sent_b = sent + gb * 16;
        for (int s = 0; s < TT; ++s) {
            const int par = s & 1;
            gather_sent(sent_b, hvals + ((size_t)par * BB + gb) * HH, lane,
                        (unsigned)s, lh[gi][par], &lflag[gi][par], s + 1);
        }
        if (sl == 0) {  // final h (published with sentinel TT) for tag_space
            gather_sent(sent_b, hvals + ((size_t)(TT & 1) * BB + gb) * HH, lane,
                        (unsigned)TT, lh[gi][0], &lflag[gi][0], TT + 1);
        }
        return;
    }

    // ================= compute waves (tid 0..511) =================
    const int wv   = tid >> 6;       // 0..7
    const int lane = tid & 63;
    const int hw   = lane >> 5;
    const int i    = lane & 31;
    const int r    = sl * 16 + wv * 2 + hw;

    float4 W4[4], L4[4], G4[4], FA[4], FB[4];
    {
        const float4* wr = reinterpret_cast<const float4*>(w    + (size_t)r * FWID);
        const float4* lr = reinterpret_cast<const float4*>(wlam + (size_t)r * FWID);
        const float4* gr = reinterpret_cast<const float4*>(wgam + (size_t)r * FWID);
#pragma unroll
        for (int k = 0; k < 4; ++k) {
            W4[k] = wr[k * 32 + i];
            L4[k] = lr[k * 32 + i];
            G4[k] = gr[k * 32 + i];
            FA[k] = make_float4(0.f, 0.f, 0.f, 0.f);
            FB[k] = make_float4(0.f, 0.f, 0.f, 0.f);
        }
    }
    const float bj = bias[r];
    float hlA = 0.f, hlB = 0.f;

    for (int s = 0; s < TT; ++s) {
        const int par = s & 1;
        const int tgt = 8 * ((s >> 1) + 1);   // counter target for this parity use

        const float4* xA = reinterpret_cast<const float4*>(x + ((size_t)bA * TT + s) * II);
        const float4* xB = reinterpret_cast<const float4*>(x + ((size_t)bB * TT + s) * II);
        float4 TA0 = xA[i], TA1 = xA[32 + i];
        float4 TB0 = xB[i], TB1 = xB[32 + i];

        // ---- Phase P: independent of h(s) ----
        float4 twA2, twA3, twB2, twB3;
        float4 dxa = make_float4(0,0,0,0), na = make_float4(0,0,0,0);
        float4 dxb = make_float4(0,0,0,0), nb = make_float4(0,0,0,0);
        {
            float4 t;
            t.x = W4[0].x + FA[0].x; t.y = W4[0].y + FA[0].y; t.z = W4[0].z + FA[0].z; t.w = W4[0].w + FA[0].w;
            dxa.x = fmaf(TA0.x, t.x, dxa.x); dxa.y = fmaf(TA0.y, t.y, dxa.y);
            dxa.z = fmaf(TA0.z, t.z, dxa.z); dxa.w = fmaf(TA0.w, t.w, dxa.w);
            na.x = fmaf(t.x, t.x, na.x); na.y = fmaf(t.y, t.y, na.y);
            na.z = fmaf(t.z, t.z, na.z); na.w = fmaf(t.w, t.w, na.w);
            t.x = W4[1].x + FA[1].x; t.y = W4[1].y + FA[1].y; t.z = W4[1].z + FA[1].z; t.w = W4[1].w + FA[1].w;
            dxa.x = fmaf(TA1.x, t.x, dxa.x); dxa.y = fmaf(TA1.y, t.y, dxa.y);
            dxa.z = fmaf(TA1.z, t.z, dxa.z); dxa.w = fmaf(TA1.w, t.w, dxa.w);
            na.x = fmaf(t.x, t.x, na.x); na.y = fmaf(t.y, t.y, na.y);
            na.z = fmaf(t.z, t.z, na.z); na.w = fmaf(t.w, t.w, na.w);
            t.x = W4[0].x + FB[0].x; t.y = W4[0].y + FB[0].y; t.z = W4[0].z + FB[0].z; t.w = W4[0].w + FB[0].w;
            dxb.x = fmaf(TB0.x, t.x, dxb.x); dxb.y = fmaf(TB0.y, t.y, dxb.y);
            dxb.z = fmaf(TB0.z, t.z, dxb.z); dxb.w = fmaf(TB0.w, t.w, dxb.w);
            nb.x = fmaf(t.x, t.x, nb.x); nb.y = fmaf(t.y, t.y, nb.y);
            nb.z = fmaf(t.z, t.z, nb.z); nb.w = fmaf(t.w, t.w, nb.w);
            t.x = W4[1].x + FB[1].x; t.y = W4[1].y + FB[1].y; t.z = W4[1].z + FB[1].z; t.w = W4[1].w + FB[1].w;
            dxb.x = fmaf(TB1.x, t.x, dxb.x); dxb.y = fmaf(TB1.y, t.y, dxb.y);
            dxb.z = fmaf(TB1.z, t.z, dxb.z); dxb.w = fmaf(TB1.w, t.w, dxb.w);
            nb.x = fmaf(t.x, t.x, nb.x); nb.y = fmaf(t.y, t.y, nb.y);
            nb.z = fmaf(t.z, t.z, nb.z); nb.w = fmaf(t.w, t.w, nb.w);
            twA2.x = W4[2].x + FA[2].x; twA2.y = W4[2].y + FA[2].y; twA2.z = W4[2].z + FA[2].z; twA2.w = W4[2].w + FA[2].w;
            na.x = fmaf(twA2.x, twA2.x, na.x); na.y = fmaf(twA2.y, twA2.y, na.y);
            na.z = fmaf(twA2.z, twA2.z, na.z); na.w = fmaf(twA2.w, twA2.w, na.w);
            twA3.x = W4[3].x + FA[3].x; twA3.y = W4[3].y + FA[3].y; twA3.z = W4[3].z + FA[3].z; twA3.w = W4[3].w + FA[3].w;
            na.x = fmaf(twA3.x, twA3.x, na.x); na.y = fmaf(twA3.y, twA3.y, na.y);
            na.z = fmaf(twA3.z, twA3.z, na.z); na.w = fmaf(twA3.w, twA3.w, na.w);
            twB2.x = W4[2].x + FB[2].x; twB2.y = W4[2].y + FB[2].y; twB2.z = W4[2].z + FB[2].z; twB2.w = W4[2].w + FB[2].w;
            nb.x = fmaf(twB2.x, twB2.x, nb.x); nb.y = fmaf(twB2.y, twB2.y, nb.y);
            nb.z = fmaf(twB2.z, twB2.z, nb.z); nb.w = fmaf(twB2.w, twB2.w, nb.w);
            twB3.x = W4[3].x + FB[3].x; twB3.y = W4[3].y + FB[3].y; twB3.z = W4[3].z + FB[3].z; twB3.w = W4[3].w + FB[3].w;
            nb.x = fmaf(twB3.x, twB3.x, nb.x); nb.y = fmaf(twB3.y, twB3.y, nb.y);
            nb.z = fmaf(twB3.z, twB3.z, nb.z); nb.w = fmaf(twB3.w, twB3.w, nb.w);
        }
        float dxA = (dxa.x + dxa.y) + (dxa.z + dxa.w);
        float nrmA = (na.x + na.y) + (na.z + na.w);
        float dxB = (dxb.x + dxb.y) + (dxb.z + dxb.w);
        float nrmB = (nb.x + nb.y) + (nb.z + nb.w);
#pragma unroll
        for (int off = 1; off <= 16; off <<= 1) {
            dxA  += __shfl_xor(dxA,  off, 64);
            nrmA += __shfl_xor(nrmA, off, 64);
            dxB  += __shfl_xor(dxB,  off, 64);
            nrmB += __shfl_xor(nrmB, off, 64);
        }
        const float invnA = 1.0f / (sqrtf(nrmA) + 1e-16f);
        const float invnB = 1.0f / (sqrtf(nrmB) + 1e-16f);

#pragma unroll
        for (int k = 0; k < 4; ++k) {
            FA[k].x = L4[k].x * (FA[k].x * invnA); FA[k].y = L4[k].y * (FA[k].y * invnA);
            FA[k].z = L4[k].z * (FA[k].z * invnA); FA[k].w = L4[k].w * (FA[k].w * invnA);
            FB[k].x = L4[k].x * (FB[k].x * invnB); FB[k].y = L4[k].y * (FB[k].y * invnB);
            FB[k].z = L4[k].z * (FB[k].z * invnB); FB[k].w = L4[k].w * (FB[k].w * invnB);
        }
        TA0.x *= G4[0].x; TA0.y *= G4[0].y; TA0.z *= G4[0].z; TA0.w *= G4[0].w;
        TA1.x *= G4[1].x; TA1.y *= G4[1].y; TA1.z *= G4[1].z; TA1.w *= G4[1].w;
        TB0.x *= G4[0].x; TB0.y *= G4[0].y; TB0.z *= G4[0].z; TB0.w *= G4[0].w;
        TB1.x *= G4[1].x; TB1.y *= G4[1].y; TB1.z *= G4[1].z; TB1.w *= G4[1].w;

        // ---- batch A critical section ----
        while (__hip_atomic_load(&lflag[0][par], __ATOMIC_ACQUIRE, __HIP_MEMORY_SCOPE_WORKGROUP) < s + 1) {}
        const float4* lA4 = reinterpret_cast<const float4*>(lh[0][par]);
        float4 TA2 = lA4[i], TA3 = lA4[32 + i];
        float dhA = fmaf(TA2.x, twA2.x, fmaf(TA2.y, twA2.y, fmaf(TA2.z, twA2.z, TA2.w * twA2.w)));
        dhA = fmaf(TA3.x, twA3.x, fmaf(TA3.y, twA3.y, fmaf(TA3.z, twA3.z, fmaf(TA3.w, twA3.w, dhA))));
#pragma unroll
        for (int off = 1; off <= 16; off <<= 1) dhA += __shfl_xor(dhA, off, 64);
        const float eA = __expf(2.0f * (dxA + dhA + bj));
        const float hA = (1.0f - 2.0f / (eA + 1.0f)) * invnA;
        hlA = hA;
        if (i == 0)
            __hip_atomic_store(hvals + ((size_t)(par ^ 1) * BB + bA) * HH + r, hA,
                               __ATOMIC_RELAXED, __HIP_MEMORY_SCOPE_AGENT);
        asm volatile("s_waitcnt vmcnt(0)" ::: "memory");   // this wave's hval stores at coherence point
        if (lane == 0) {
            int ret = __hip_atomic_fetch_add(&dctr[0][par], 1, __ATOMIC_RELEASE, __HIP_MEMORY_SCOPE_WORKGROUP);
            if (ret == tgt - 1)   // last wave: all 16 rows of (bA, sl) published
                __hip_atomic_store(sent + bA * 16 + sl, (unsigned)(s + 1),
                                   __ATOMIC_RELAXED, __HIP_MEMORY_SCOPE_AGENT);
        }

        // ---- batch B critical section ----
        while (__hip_atomic_load(&lflag[1][par], __ATOMIC_ACQUIRE, __HIP_MEMORY_SCOPE_WORKGROUP) < s + 1) {}
        const float4* lB4 = reinterpret_cast<const float4*>(lh[1][par]);
        float4 TB2 = lB4[i], TB3 = lB4[32 + i];
        float dhB = fmaf(TB2.x, twB2.x, fmaf(TB2.y, twB2.y, fmaf(TB2.z, twB2.z, TB2.w * twB2.w)));
        dhB = fmaf(TB3.x, twB3.x, fmaf(TB3.y, twB3.y, fmaf(TB3.z, twB3.z, fmaf(TB3.w, twB3.w, dhB))));
#pragma unroll
        for (int off = 1; off <= 16; off <<= 1) dhB += __shfl_xor(dhB, off, 64);
        const float eB = __expf(2.0f * (dxB + dhB + bj));
        const float hB = (1.0f - 2.0f / (eB + 1.0f)) * invnB;
        hlB = hB;
        if (i == 0)
            __hip_atomic_store(hvals + ((size_t)(par ^ 1) * BB + bB) * HH + r, hB,
                               __ATOMIC_RELAXED, __HIP_MEMORY_SCOPE_AGENT);
        asm volatile("s_waitcnt vmcnt(0)" ::: "memory");
        if (lane == 0) {
            int ret = __hip_atomic_fetch_add(&dctr[1][par], 1, __ATOMIC_RELEASE, __HIP_MEMORY_SCOPE_WORKGROUP);
            if (ret == tgt - 1)
                __hip_atomic_store(sent + bB * 16 + sl, (unsigned)(s + 1),
                                   __ATOMIC_RELAXED, __HIP_MEMORY_SCOPE_AGENT);
        }

        // ---- Phase U: F += (gamma*t)*h ----
        FA[0].x = fmaf(TA0.x, hA, FA[0].x); FA[0].y = fmaf(TA0.y, hA, FA[0].y);
        FA[0].z = fmaf(TA0.z, hA, FA[0].z); FA[0].w = fmaf(TA0.w, hA, FA[0].w);
        FA[1].x = fmaf(TA1.x, hA, FA[1].x); FA[1].y = fmaf(TA1.y, hA, FA[1].y);
        FA[1].z = fmaf(TA1.z, hA, FA[1].z); FA[1].w = fmaf(TA1.w, hA, FA[1].w);
        FA[2].x = fmaf(G4[2].x * TA2.x, hA, FA[2].x); FA[2].y = fmaf(G4[2].y * TA2.y, hA, FA[2].y);
        FA[2].z = fmaf(G4[2].z * TA2.z, hA, FA[2].z); FA[2].w = fmaf(G4[2].w * TA2.w, hA, FA[2].w);
        FA[3].x = fmaf(G4[3].x * TA3.x, hA, FA[3].x); FA[3].y = fmaf(G4[3].y * TA3.y, hA, FA[3].y);
        FA[3].z = fmaf(G4[3].z * TA3.z, hA, FA[3].z); FA[3].w = fmaf(G4[3].w * TA3.w, hA, FA[3].w);
        FB[0].x = fmaf(TB0.x, hB, FB[0].x); FB[0].y = fmaf(TB0.y, hB, FB[0].y);
        FB[0].z = fmaf(TB0.z, hB, FB[0].z); FB[0].w = fmaf(TB0.w, hB, FB[0].w);
        FB[1].x = fmaf(TB1.x, hB, FB[1].x); FB[1].y = fmaf(TB1.y, hB, FB[1].y);
        FB[1].z = fmaf(TB1.z, hB, FB[1].z); FB[1].w = fmaf(TB1.w, hB, FB[1].w);
        FB[2].x = fmaf(G4[2].x * TB2.x, hB, FB[2].x); FB[2].y = fmaf(G4[2].y * TB2.y, hB, FB[2].y);
        FB[2].z = fmaf(G4[2].z * TB2.z, hB, FB[2].z); FB[2].w = fmaf(G4[2].w * TB2.w, hB, FB[2].w);
        FB[3].x = fmaf(G4[3].x * TB3.x, hB, FB[3].x); FB[3].y = fmaf(G4[3].y * TB3.y, hB, FB[3].y);
        FB[3].z = fmaf(G4[3].z * TB3.z, hB, FB[3].z); FB[3].w = fmaf(G4[3].w * TB3.w, hB, FB[3].w);
    }

    // ---- epilogue: F_T, h_T ----
    {
        float4* oA = reinterpret_cast<float4*>(out + 12288 + ((size_t)bA * HH + r) * FWID);
        float4* oB = reinterpret_cast<float4*>(out + 12288 + ((size_t)bB * HH + r) * FWID);
#pragma unroll
        for (int k = 0; k < 4; ++k) { oA[k * 32 + i] = FA[k]; oB[k * 32 + i] = FB[k]; }
    }
    if (i == 0) {
        out[4096 + (size_t)bA * HH + r] = hlA;
        out[4096 + (size_t)bB * HH + r] = hlB;
    }

    // ---- tag_space: slice-0 compute waves; gatherers flagged TT+1 into lh[*][0] ----
    if (sl == 0) {
        while (__hip_atomic_load(&lflag[0][0], __ATOMIC_ACQUIRE, __HIP_MEMORY_SCOPE_WORKGROUP) < TT + 1) {}
        while (__hip_atomic_load(&lflag[1][0], __ATOMIC_ACQUIRE, __HIP_MEMORY_SCOPE_WORKGROUP) < TT + 1) {}
        if (tid < 2 * OO) {
            const int bt = tid >> 7;
            const int o  = tid & 127;
            const float* hv = lh[bt][0];
            float acc = bout[o];
            const float* wo = wout + (size_t)o * HH;
#pragma unroll 4
            for (int jj = 0; jj < HH; ++jj) acc = fmaf(wo[jj], hv[jj], acc);
            out[(size_t)(bt ? bB : bA) * OO + o] = acc;
        }
    }
}

extern "C" void kernel_launch(void* const* d_in, const int* in_sizes, int n_in,
                              void* d_out, int out_size, void* d_ws, size_t ws_size,
                              hipStream_t stream) {
    (void)in_sizes; (void)n_in; (void)out_size; (void)ws_size;
    const float* x    = (const float*)d_in[0];
    const float* wlam = (const float*)d_in[1];
    const float* wgam = (const float*)d_in[2];
    const float* w    = (const float*)d_in[3];
    const float* bias = (const float*)d_in[4];
    const float* wout = (const float*)d_in[5];
    const float* bout = (const float*)d_in[6];
    float* out = (float*)d_out;

    float* hvals   = (float*)d_ws;
    unsigned* sent = (unsigned*)((char*)d_ws + 2ull * BB * HH * 4ull);

    // hvals = 0 (h(0)=0), sent = 0 (>= 0 satisfies step-0 gather)
    hipMemsetAsync(d_ws, 0, 2ull * BB * HH * 4ull + (size_t)BB * 16 * 4ull, stream);

    void* args[] = {(void*)&x, (void*)&wlam, (void*)&wgam, (void*)&w, (void*)&bias,
                    (void*)&wout, (void*)&bout, (void*)&out, (void*)&hvals, (void*)&sent};
    hipLaunchCooperativeKernel((void*)stpn_kernel, dim3(256), dim3(640), args, 0, stream);
}

// Round 8
// 323.710 us; speedup vs baseline: 3.0889x; 3.0889x over previous
//
#include <hip/hip_runtime.h>

#define BB 32
#define TT 128
#define II 256
#define HH 256
#define OO 128
#define FWID 512  // H + I

// d_ws: u64 slots[2][BB][HH] (parity, batch, row) = 128 KB.
// Slot = (stamp<<32)|float_bits(h); step s consumes stamp>=s from parity s&1,
// publishes stamp s+1 into parity (s+1)&1. All slot traffic agent-scope relaxed
// (no fences) -- protocol correctness proven on HW in R2/R3/R5 runs.
// Overwrite safety: producer writes stamp s+2 (same parity as stamp s) only in
// step s+1, gated on its gather(s+1) = all rows at stamp s+1 = every block
// exited its stamp-s gather loop (all stamp-s reads complete). LDS lh[par]
// overwrite safety: gather(s) completing implies all 16 blocks' waves published
// stamp s, which post-dates their consume(s-1) reads of lh[par^1] and (by
// program order) their consume(s-2) reads of lh[par]. u64 atomics cannot tear.
//
// R8 change vs R5 (327 us): the gatherer waves run Phase P BEFORE the gather
// spin. In R5 the gatherer's ~1500-2000 cy Phase P sat between its flag and its
// publish -- its rows were the last published every step, gating every other
// block's next gather. Pipelined, remote publishes propagate during Phase P and
// the post-arrival chain is only detect + flag + dot_h/tanh + publish.

typedef unsigned long long u64;

__device__ __forceinline__ u64 slot_ld(const u64* p) {
    return __hip_atomic_load(p, __ATOMIC_RELAXED, __HIP_MEMORY_SCOPE_AGENT);
}

// One wave gathers 256 rows of one batch (4 slots/lane, issued concurrently),
// stages h to LDS (ds_write_b128), release-stores an LDS flag.
__device__ __forceinline__ void gather_to_lds(const u64* base, int lane, unsigned us,
                                              float* dst, int* flag, int fval) {
    const u64* p = base + 4 * lane;
    u64 a, b, c, d;
    for (;;) {
        a = slot_ld(p);
        b = slot_ld(p + 1);
        c = slot_ld(p + 2);
        d = slot_ld(p + 3);
        bool ok = ((unsigned)(a >> 32) >= us) & ((unsigned)(b >> 32) >= us) &
                  ((unsigned)(c >> 32) >= us) & ((unsigned)(d >> 32) >= us);
        if (__all(ok)) break;
    }
    float4 hv;
    hv.x = __uint_as_float((unsigned)a);
    hv.y = __uint_as_float((unsigned)b);
    hv.z = __uint_as_float((unsigned)c);
    hv.w = __uint_as_float((unsigned)d);
    *reinterpret_cast<float4*>(dst + 4 * lane) = hv;
    if (lane == 0)  // release drains the wave's ds_write before the flag
        __hip_atomic_store(flag, fval, __ATOMIC_RELEASE, __HIP_MEMORY_SCOPE_WORKGROUP);
}

__global__ __launch_bounds__(512, 2)
void stpn_kernel(const float* __restrict__ x,      // (B,T,I)
                 const float* __restrict__ wlam,   // (H,FWID)
                 const float* __restrict__ wgam,   // (H,FWID)
                 const float* __restrict__ w,      // (H,FWID)
                 const float* __restrict__ bias,   // (H)
                 const float* __restrict__ wout,   // (O,H)
                 const float* __restrict__ bout,   // (O)
                 float* __restrict__ out,          // tag(4096) | h_T(8192) | F_T
                 u64* __restrict__ slots)
{
    __shared__ __align__(16) float lh[2][2][HH];   // [A/B][parity][row]
    __shared__ int lflag[2][2];                    // [A/B][parity]

    const int tid  = threadIdx.x;
    const int bk   = blockIdx.x;
    const int pr   = bk & 15;        // batch pair: batches pr, pr+16
    const int sl   = bk >> 4;        // row slice 0..15
    const int wv   = tid >> 6;
    const int lane = tid & 63;
    const int hw   = lane >> 5;
    const int i    = lane & 31;
    const int r    = sl * 16 + wv * 2 + hw;
    const int bA   = pr, bB = pr + 16;

    if (tid < 4) ((int*)lflag)[tid] = 0;

    float4 W4[4], L4[4], G4[4], FA[4], FB[4];
    {
        const float4* wr = reinterpret_cast<const float4*>(w    + (size_t)r * FWID);
        const float4* lr = reinterpret_cast<const float4*>(wlam + (size_t)r * FWID);
        const float4* gr = reinterpret_cast<const float4*>(wgam + (size_t)r * FWID);
#pragma unroll
        for (int k = 0; k < 4; ++k) {
            W4[k] = wr[k * 32 + i];
            L4[k] = lr[k * 32 + i];
            G4[k] = gr[k * 32 + i];
            FA[k] = make_float4(0.f, 0.f, 0.f, 0.f);
            FB[k] = make_float4(0.f, 0.f, 0.f, 0.f);
        }
    }
    const float bj = bias[r];
    float hlA = 0.f, hlB = 0.f;

    __syncthreads();   // lflag init visible

    for (int s = 0; s < TT; ++s) {
        const int par = s & 1;

        // x loads (independent, L2-resident after first pass)
        const float4* xA = reinterpret_cast<const float4*>(x + ((size_t)bA * TT + s) * II);
        const float4* xB = reinterpret_cast<const float4*>(x + ((size_t)bB * TT + s) * II);
        float4 TA0 = xA[i], TA1 = xA[32 + i];
        float4 TB0 = xB[i], TB1 = xB[32 + i];

        // ---- Phase P: independent of h(s) -- runs BEFORE the gather (R8) ----
        float4 twA2, twA3, twB2, twB3;
        float4 dxa = make_float4(0,0,0,0), na = make_float4(0,0,0,0);
        float4 dxb = make_float4(0,0,0,0), nb = make_float4(0,0,0,0);
        {
            float4 t;
            t.x = W4[0].x + FA[0].x; t.y = W4[0].y + FA[0].y; t.z = W4[0].z + FA[0].z; t.w = W4[0].w + FA[0].w;
            dxa.x = fmaf(TA0.x, t.x, dxa.x); dxa.y = fmaf(TA0.y, t.y, dxa.y);
            dxa.z = fmaf(TA0.z, t.z, dxa.z); dxa.w = fmaf(TA0.w, t.w, dxa.w);
            na.x = fmaf(t.x, t.x, na.x); na.y = fmaf(t.y, t.y, na.y);
            na.z = fmaf(t.z, t.z, na.z); na.w = fmaf(t.w, t.w, na.w);
            t.x = W4[1].x + FA[1].x; t.y = W4[1].y + FA[1].y; t.z = W4[1].z + FA[1].z; t.w = W4[1].w + FA[1].w;
            dxa.x = fmaf(TA1.x, t.x, dxa.x); dxa.y = fmaf(TA1.y, t.y, dxa.y);
            dxa.z = fmaf(TA1.z, t.z, dxa.z); dxa.w = fmaf(TA1.w, t.w, dxa.w);
            na.x = fmaf(t.x, t.x, na.x); na.y = fmaf(t.y, t.y, na.y);
            na.z = fmaf(t.z, t.z, na.z); na.w = fmaf(t.w, t.w, na.w);
            t.x = W4[0].x + FB[0].x; t.y = W4[0].y + FB[0].y; t.z = W4[0].z + FB[0].z; t.w = W4[0].w + FB[0].w;
            dxb.x = fmaf(TB0.x, t.x, dxb.x); dxb.y = fmaf(TB0.y, t.y, dxb.y);
            dxb.z = fmaf(TB0.z, t.z, dxb.z); dxb.w = fmaf(TB0.w, t.w, dxb.w);
            nb.x = fmaf(t.x, t.x, nb.x); nb.y = fmaf(t.y, t.y, nb.y);
            nb.z = fmaf(t.z, t.z, nb.z); nb.w = fmaf(t.w, t.w, nb.w);
            t.x = W4[1].x + FB[1].x; t.y = W4[1].y + FB[1].y; t.z = W4[1].z + FB[1].z; t.w = W4[1].w + FB[1].w;
            dxb.x = fmaf(TB1.x, t.x, dxb.x); dxb.y = fmaf(TB1.y, t.y, dxb.y);
            dxb.z = fmaf(TB1.z, t.z, dxb.z); dxb.w = fmaf(TB1.w, t.w, dxb.w);
            nb.x = fmaf(t.x, t.x, nb.x); nb.y = fmaf(t.y, t.y, nb.y);
            nb.z = fmaf(t.z, t.z, nb.z); nb.w = fmaf(t.w, t.w, nb.w);
            twA2.x = W4[2].x + FA[2].x; twA2.y = W4[2].y + FA[2].y; twA2.z = W4[2].z + FA[2].z; twA2.w = W4[2].w + FA[2].w;
            na.x = fmaf(twA2.x, twA2.x, na.x); na.y = fmaf(twA2.y, twA2.y, na.y);
            na.z = fmaf(twA2.z, twA2.z, na.z); na.w = fmaf(twA2.w, twA2.w, na.w);
            twA3.x = W4[3].x + FA[3].x; twA3.y = W4[3].y + FA[3].y; twA3.z = W4[3].z + FA[3].z; twA3.w = W4[3].w + FA[3].w;
            na.x = fmaf(twA3.x, twA3.x, na.x); na.y = fmaf(twA3.y, twA3.y, na.y);
            na.z = fmaf(twA3.z, twA3.z, na.z); na.w = fmaf(twA3.w, twA3.w, na.w);
            twB2.x = W4[2].x + FB[2].x; twB2.y = W4[2].y + FB[2].y; twB2.z = W4[2].z + FB[2].z; twB2.w = W4[2].w + FB[2].w;
            nb.x = fmaf(twB2.x, twB2.x, nb.x); nb.y = fmaf(twB2.y, twB2.y, nb.y);
            nb.z = fmaf(twB2.z, twB2.z, nb.z); nb.w = fmaf(twB2.w, twB2.w, nb.w);
            twB3.x = W4[3].x + FB[3].x; twB3.y = W4[3].y + FB[3].y; twB3.z = W4[3].z + FB[3].z; twB3.w = W4[3].w + FB[3].w;
            nb.x = fmaf(twB3.x, twB3.x, nb.x); nb.y = fmaf(twB3.y, twB3.y, nb.y);
            nb.z = fmaf(twB3.z, twB3.z, nb.z); nb.w = fmaf(twB3.w, twB3.w, nb.w);
        }
        float dxA = (dxa.x + dxa.y) + (dxa.z + dxa.w);
        float nrmA = (na.x + na.y) + (na.z + na.w);
        float dxB = (dxb.x + dxb.y) + (dxb.z + dxb.w);
        float nrmB = (nb.x + nb.y) + (nb.z + nb.w);
#pragma unroll
        for (int off = 1; off <= 16; off <<= 1) {
            dxA  += __shfl_xor(dxA,  off, 64);
            nrmA += __shfl_xor(nrmA, off, 64);
            dxB  += __shfl_xor(dxB,  off, 64);
            nrmB += __shfl_xor(nrmB, off, 64);
        }
        const float invnA = 1.0f / (sqrtf(nrmA) + 1e-16f);
        const float invnB = 1.0f / (sqrtf(nrmB) + 1e-16f);

#pragma unroll
        for (int k = 0; k < 4; ++k) {
            FA[k].x = L4[k].x * (FA[k].x * invnA); FA[k].y = L4[k].y * (FA[k].y * invnA);
            FA[k].z = L4[k].z * (FA[k].z * invnA); FA[k].w = L4[k].w * (FA[k].w * invnA);
            FB[k].x = L4[k].x * (FB[k].x * invnB); FB[k].y = L4[k].y * (FB[k].y * invnB);
            FB[k].z = L4[k].z * (FB[k].z * invnB); FB[k].w = L4[k].w * (FB[k].w * invnB);
        }
        TA0.x *= G4[0].x; TA0.y *= G4[0].y; TA0.z *= G4[0].z; TA0.w *= G4[0].w;
        TA1.x *= G4[1].x; TA1.y *= G4[1].y; TA1.z *= G4[1].z; TA1.w *= G4[1].w;
        TB0.x *= G4[0].x; TB0.y *= G4[0].y; TB0.z *= G4[0].z; TB0.w *= G4[0].w;
        TB1.x *= G4[1].x; TB1.y *= G4[1].y; TB1.z *= G4[1].z; TB1.w *= G4[1].w;

        // ---- gather (pipelined after Phase P): stamps likely already arrived ----
        if (wv < 2) {
            const u64* gbase = slots + ((size_t)par * BB + (wv ? bB : bA)) * HH;
            gather_to_lds(gbase, lane, (unsigned)s, lh[wv][par], &lflag[wv][par], s + 1);
        }

        // ---- Phase W: LDS flag spin (local), consume h ----
        while (__hip_atomic_load(&lflag[0][par], __ATOMIC_ACQUIRE, __HIP_MEMORY_SCOPE_WORKGROUP) <= s) {}
        while (__hip_atomic_load(&lflag[1][par], __ATOMIC_ACQUIRE, __HIP_MEMORY_SCOPE_WORKGROUP) <= s) {}
        const float4* lA4 = reinterpret_cast<const float4*>(lh[0][par]);
        const float4* lB4 = reinterpret_cast<const float4*>(lh[1][par]);
        float4 TA2 = lA4[i], TA3 = lA4[32 + i];
        float4 TB2 = lB4[i], TB3 = lB4[32 + i];

        float dhA = fmaf(TA2.x, twA2.x, fmaf(TA2.y, twA2.y, fmaf(TA2.z, twA2.z, TA2.w * twA2.w)));
        dhA = fmaf(TA3.x, twA3.x, fmaf(TA3.y, twA3.y, fmaf(TA3.z, twA3.z, fmaf(TA3.w, twA3.w, dhA))));
        float dhB = fmaf(TB2.x, twB2.x, fmaf(TB2.y, twB2.y, fmaf(TB2.z, twB2.z, TB2.w * twB2.w)));
        dhB = fmaf(TB3.x, twB3.x, fmaf(TB3.y, twB3.y, fmaf(TB3.z, twB3.z, fmaf(TB3.w, twB3.w, dhB))));
#pragma unroll
        for (int off = 1; off <= 16; off <<= 1) {
            dhA += __shfl_xor(dhA, off, 64);
            dhB += __shfl_xor(dhB, off, 64);
        }

        const float eA = __expf(2.0f * (dxA + dhA + bj));
        const float eB = __expf(2.0f * (dxB + dhB + bj));
        const float hA = (1.0f - 2.0f / (eA + 1.0f)) * invnA;
        const float hB = (1.0f - 2.0f / (eB + 1.0f)) * invnB;
        hlA = hA; hlB = hB;

        // publish ASAP (relaxed agent stores, no fence)
        if (i == 0) {
            const u64 st = (u64)(unsigned)(s + 1) << 32;
            __hip_atomic_store(slots + ((size_t)(par ^ 1) * BB + bA) * HH + r,
                               st | (unsigned)__float_as_uint(hA),
                               __ATOMIC_RELAXED, __HIP_MEMORY_SCOPE_AGENT);
            __hip_atomic_store(slots + ((size_t)(par ^ 1) * BB + bB) * HH + r,
                               st | (unsigned)__float_as_uint(hB),
                               __ATOMIC_RELAXED, __HIP_MEMORY_SCOPE_AGENT);
        }

        // ---- Phase U: F += (gamma*t)*h ----
        FA[0].x = fmaf(TA0.x, hA, FA[0].x); FA[0].y = fmaf(TA0.y, hA, FA[0].y);
        FA[0].z = fmaf(TA0.z, hA, FA[0].z); FA[0].w = fmaf(TA0.w, hA, FA[0].w);
        FA[1].x = fmaf(TA1.x, hA, FA[1].x); FA[1].y = fmaf(TA1.y, hA, FA[1].y);
        FA[1].z = fmaf(TA1.z, hA, FA[1].z); FA[1].w = fmaf(TA1.w, hA, FA[1].w);
        FA[2].x = fmaf(G4[2].x * TA2.x, hA, FA[2].x); FA[2].y = fmaf(G4[2].y * TA2.y, hA, FA[2].y);
        FA[2].z = fmaf(G4[2].z * TA2.z, hA, FA[2].z); FA[2].w = fmaf(G4[2].w * TA2.w, hA, FA[2].w);
        FA[3].x = fmaf(G4[3].x * TA3.x, hA, FA[3].x); FA[3].y = fmaf(G4[3].y * TA3.y, hA, FA[3].y);
        FA[3].z = fmaf(G4[3].z * TA3.z, hA, FA[3].z); FA[3].w = fmaf(G4[3].w * TA3.w, hA, FA[3].w);
        FB[0].x = fmaf(TB0.x, hB, FB[0].x); FB[0].y = fmaf(TB0.y, hB, FB[0].y);
        FB[0].z = fmaf(TB0.z, hB, FB[0].z); FB[0].w = fmaf(TB0.w, hB, FB[0].w);
        FB[1].x = fmaf(TB1.x, hB, FB[1].x); FB[1].y = fmaf(TB1.y, hB, FB[1].y);
        FB[1].z = fmaf(TB1.z, hB, FB[1].z); FB[1].w = fmaf(TB1.w, hB, FB[1].w);
        FB[2].x = fmaf(G4[2].x * TB2.x, hB, FB[2].x); FB[2].y = fmaf(G4[2].y * TB2.y, hB, FB[2].y);
        FB[2].z = fmaf(G4[2].z * TB2.z, hB, FB[2].z); FB[2].w = fmaf(G4[2].w * TB2.w, hB, FB[2].w);
        FB[3].x = fmaf(G4[3].x * TB3.x, hB, FB[3].x); FB[3].y = fmaf(G4[3].y * TB3.y, hB, FB[3].y);
        FB[3].z = fmaf(G4[3].z * TB3.z, hB, FB[3].z); FB[3].w = fmaf(G4[3].w * TB3.w, hB, FB[3].w);
    }

    // ---- epilogue: F_T, h_T ----
    {
        float4* oA = reinterpret_cast<float4*>(out + 12288 + ((size_t)bA * HH + r) * FWID);
        float4* oB = reinterpret_cast<float4*>(out + 12288 + ((size_t)bB * HH + r) * FWID);
#pragma unroll
        for (int k = 0; k < 4; ++k) { oA[k * 32 + i] = FA[k]; oB[k * 32 + i] = FB[k]; }
    }
    if (i == 0) {
        out[4096 + (size_t)bA * HH + r] = hlA;
        out[4096 + (size_t)bB * HH + r] = hlB;
    }

    // tag_space: slice-0 blocks gather final h (stamp TT, parity TT&1 == 0)
    if (sl == 0) {
        if (wv < 2) {
            const u64* gbase = slots + ((size_t)(TT & 1) * BB + (wv ? bB : bA)) * HH;
            gather_to_lds(gbase, lane, (unsigned)TT, lh[wv][0], &lflag[wv][0], TT + 1);
        }
        while (__hip_atomic_load(&lflag[0][0], __ATOMIC_ACQUIRE, __HIP_MEMORY_SCOPE_WORKGROUP) <= TT) {}
        while (__hip_atomic_load(&lflag[1][0], __ATOMIC_ACQUIRE, __HIP_MEMORY_SCOPE_WORKGROUP) <= TT) {}
        if (tid < 2 * OO) {
            const int bt = tid >> 7;
            const int o  = tid & 127;
            const float* hv = lh[bt][0];
            float acc = bout[o];
            const float* wo = wout + (size_t)o * HH;
#pragma unroll 4
            for (int jj = 0; jj < HH; ++jj) acc = fmaf(wo[jj], hv[jj], acc);
            out[(size_t)(bt ? bB : bA) * OO + o] = acc;
        }
    }
}

extern "C" void kernel_launch(void* const* d_in, const int* in_sizes, int n_in,
                              void* d_out, int out_size, void* d_ws, size_t ws_size,
                              hipStream_t stream) {
    (void)in_sizes; (void)n_in; (void)out_size; (void)ws_size;
    const float* x    = (const float*)d_in[0];
    const float* wlam = (const float*)d_in[1];
    const float* wgam = (const float*)d_in[2];
    const float* w    = (const float*)d_in[3];
    const float* bias = (const float*)d_in[4];
    const float* wout = (const float*)d_in[5];
    const float* bout = (const float*)d_in[6];
    float* out = (float*)d_out;

    u64* slots = (u64*)d_ws;

    // stamp 0 + h = 0.0 is exactly what step 0 consumes
    hipMemsetAsync(d_ws, 0, 2ull * BB * HH * 8ull, stream);

    void* args[] = {(void*)&x, (void*)&wlam, (void*)&wgam, (void*)&w, (void*)&bias,
                    (void*)&wout, (void*)&bout, (void*)&out, (void*)&slots};
    hipLaunchCooperativeKernel((void*)stpn_kernel, dim3(256), dim3(512), args, 0, stream);
}